// Round 8
// baseline (123.730 us; speedup 1.0000x reference)
//
#include <hip/hip_runtime.h>
#include <hip/hip_bf16.h>

// VQ quantizer: ze [65536 x 128] f32, codebook [2048 x 128] f32.
// out[m,:] = codebook[argmin_k ||z_m - c_k||^2, :]
//
// Round 15: revert R14's packed-u32 epilogue (scores go negative ~ -||z||^2;
// u32 order broke -> wrong codes). Back to R13's proven float top-2
// (88 us, absmax 0), plus:
//  (1) block split for phase diversity: 128 threads (2 waves), 64 rows,
//      grid 1024 -> 4 independent blocks/CU (was 2). Per-wave structure,
//      math, and score stream BIT-IDENTICAL to R13; only row->block
//      mapping changes. Barriers sync 2 waves; SIMD-mates come from
//      different blocks -> antiphase fills the ~45% neither-pipe gap.
//  (2) m2 update as min(max(s,m1),m2) (== R13 semantics incl. ties;
//      compiler may fuse to v_med3_f32).
// THR 0.04 (R13-proven).
//  vq_prepn:  codebook -> 2-level i8 (pre-swizzled chunks); cn[k]=||c_k||^2;
//             g_scl[k] = per-code scale.
//  vq_score:  i8 MFMA scores, per-row streaming top-2, flag margin < THR.
//  vq_rescue: exact-fp32 rescan of flagged rows, deterministic first-index.
//  vq_fix:    outIdx[row] = low32(g_res[row]).
//  vq_gather: out = codebook[idx].

#define VQ_D 128
#define VQ_K 2048
#define VQ_M 65536
#define VQ_THR 0.04f

typedef short short8 __attribute__((ext_vector_type(8)));
typedef int  int4v  __attribute__((ext_vector_type(4)));
typedef int  i32x16 __attribute__((ext_vector_type(16)));
typedef unsigned long long u64;

// codebook, 2-level i8, pre-swizzled: row r = 16 chunks of 16B; logical
// chunk c (0-7 = level-1 bytes, 8-15 = level-2 bytes) stored at position
// c ^ (r&15). 512 KB total.
__device__ uint4 g_cbi[VQ_K * 16];
__device__ float g_scl[VQ_K];      // per-code level-1 scale s1c
__device__ int   g_list[VQ_M];
__device__ u64   g_res[VQ_M];
__device__ int   g_count;

// prep: thread g handles 8 elems of row g>>4 (16 threads/row)
__global__ void vq_prepn(const float* __restrict__ cb, float* __restrict__ cn) {
    int g = blockIdx.x * 256 + threadIdx.x;          // 0..32767
    int r = g >> 4, t = g & 15;
    const float4* s = reinterpret_cast<const float4*>(cb) + (size_t)g * 2;
    float4 f0 = s[0], f1 = s[1];
    float z[8] = {f0.x, f0.y, f0.z, f0.w, f1.x, f1.y, f1.z, f1.w};
    float ss = ((z[0]*z[0] + z[1]*z[1]) + (z[2]*z[2] + z[3]*z[3]))
             + ((z[4]*z[4] + z[5]*z[5]) + (z[6]*z[6] + z[7]*z[7]));
    float ax = fmaxf(fmaxf(fmaxf(fabsf(z[0]), fabsf(z[1])), fmaxf(fabsf(z[2]), fabsf(z[3]))),
                     fmaxf(fmaxf(fabsf(z[4]), fabsf(z[5])), fmaxf(fabsf(z[6]), fabsf(z[7]))));
    ss += __shfl_xor(ss, 1); ax = fmaxf(ax, __shfl_xor(ax, 1));
    ss += __shfl_xor(ss, 2); ax = fmaxf(ax, __shfl_xor(ax, 2));
    ss += __shfl_xor(ss, 4); ax = fmaxf(ax, __shfl_xor(ax, 4));
    ss += __shfl_xor(ss, 8); ax = fmaxf(ax, __shfl_xor(ax, 8));
    float mx  = fmaxf(ax, 1e-20f);
    float s1  = mx * (1.0f / 127.0f);
    float inv = 127.0f / mx;
    float inv2 = inv * 256.0f;
    int qa[8], qr[8];
    #pragma unroll
    for (int i = 0; i < 8; ++i) {
        float qf = rintf(z[i] * inv);
        float r1 = fmaf(-qf, s1, z[i]);
        float q2f = fminf(127.f, fmaxf(-127.f, rintf(r1 * inv2)));
        qa[i] = (int)qf; qr[i] = (int)q2f;
    }
    uint2 w1, w2;
    w1.x = (qa[0]&255) | ((qa[1]&255)<<8) | ((qa[2]&255)<<16) | ((unsigned)(qa[3]&255)<<24);
    w1.y = (qa[4]&255) | ((qa[5]&255)<<8) | ((qa[6]&255)<<16) | ((unsigned)(qa[7]&255)<<24);
    w2.x = (qr[0]&255) | ((qr[1]&255)<<8) | ((qr[2]&255)<<16) | ((unsigned)(qr[3]&255)<<24);
    w2.y = (qr[4]&255) | ((qr[5]&255)<<8) | ((qr[6]&255)<<16) | ((unsigned)(qr[7]&255)<<24);
    uint2* cw = reinterpret_cast<uint2*>(g_cbi);
    int c1 = (t >> 1) ^ (r & 15);
    int c2 = (8 + (t >> 1)) ^ (r & 15);
    cw[(r * 16 + c1) * 2 + (t & 1)] = w1;
    cw[(r * 16 + c2) * 2 + (t & 1)] = w2;
    if (t == 0) { cn[r] = ss; g_scl[r] = s1; }
    if (g == 0) g_count = 0;
}

__global__ __launch_bounds__(128)
void vq_score(const float* __restrict__ ze,
              const float* __restrict__ cn,
              int* __restrict__ outIdx) {
    __shared__ uint4 sB[2048];   // 32 KB: prologue A staging (first 16 KB);
                                 // main loop: double-buffered B tile (2 x 16 KB).
    const int tid  = threadIdx.x;
    const int lane = tid & 63;
    const int wv   = tid >> 6;          // 0..1, wave owns 32 query rows
    const int ln31 = lane & 31;
    const int g2   = lane >> 5;         // 0/1: k-half selector
    const int qb   = blockIdx.x * 64;   // 64 rows per block

    // ---- prologue: 2-level i8 quantize; rows are WAVE-OWNED:
    //      id = wv*512 + jj*64 + lane -> row r = wv*32 + jj*4 + (lane>>4)
    uint2 q1w[8], q2w[8];
    float s1r[8];                       // this lane's 16-group row scale, per jj
    #pragma unroll
    for (int jj = 0; jj < 8; ++jj) {
        int id = wv * 512 + jj * 64 + lane, r = id >> 4, t = id & 15;
        const float4* src =
            reinterpret_cast<const float4*>(ze + (size_t)(qb + r) * VQ_D + t * 8);
        float4 f0 = src[0], f1 = src[1];
        float z[8] = {f0.x, f0.y, f0.z, f0.w, f1.x, f1.y, f1.z, f1.w};
        float ax = fmaxf(fmaxf(fmaxf(fabsf(z[0]), fabsf(z[1])), fmaxf(fabsf(z[2]), fabsf(z[3]))),
                         fmaxf(fmaxf(fabsf(z[4]), fabsf(z[5])), fmaxf(fabsf(z[6]), fabsf(z[7]))));
        ax = fmaxf(ax, __shfl_xor(ax, 1));
        ax = fmaxf(ax, __shfl_xor(ax, 2));
        ax = fmaxf(ax, __shfl_xor(ax, 4));
        ax = fmaxf(ax, __shfl_xor(ax, 8));
        float mx  = fmaxf(ax, 1e-20f);
        float s1  = mx * (1.0f / 127.0f);
        float inv = 127.0f / mx;
        float inv2 = inv * 256.0f;
        s1r[jj] = s1;
        int qa[8], qr[8];
        #pragma unroll
        for (int i = 0; i < 8; ++i) {
            float qf = rintf(z[i] * inv);
            float r1 = fmaf(-qf, s1, z[i]);
            float q2f = fminf(127.f, fmaxf(-127.f, rintf(r1 * inv2)));
            qa[i] = (int)qf; qr[i] = (int)q2f;
        }
        q1w[jj].x = (qa[0]&255) | ((qa[1]&255)<<8) | ((qa[2]&255)<<16) | ((unsigned)(qa[3]&255)<<24);
        q1w[jj].y = (qa[4]&255) | ((qa[5]&255)<<8) | ((qa[6]&255)<<16) | ((unsigned)(qa[7]&255)<<24);
        q2w[jj].x = (qr[0]&255) | ((qr[1]&255)<<8) | ((qr[2]&255)<<16) | ((unsigned)(qr[3]&255)<<24);
        q2w[jj].y = (qr[4]&255) | ((qr[5]&255)<<8) | ((qr[6]&255)<<16) | ((unsigned)(qr[7]&255)<<24);
    }
    {
        uint2* sw = reinterpret_cast<uint2*>(sB);
        #pragma unroll
        for (int jj = 0; jj < 8; ++jj) {
            int id = wv * 512 + jj * 64 + lane, r = id >> 4, t = id & 15;
            int c1 = (t >> 1) ^ (r & 15);
            int c2 = (8 + (t >> 1)) ^ (r & 15);
            sw[(r * 16 + c1) * 2 + (t & 1)] = q1w[jj];
            sw[(r * 16 + c2) * 2 + (t & 1)] = q2w[jj];
        }
    }
    // per-row scale -> mj[j] via shfl (row-in-wave rl = (j&3)+8*(j>>2)+4*g2;
    // scale held in s1r[rl>>2] at lane (rl&3)*16; rl>>2 = 2*(j>>2)+g2)
    float mj[16];
    #pragma unroll
    for (int j = 0; j < 16; ++j) {
        float va = __shfl(s1r[2 * (j >> 2)],     (j & 3) << 4);
        float vb = __shfl(s1r[2 * (j >> 2) + 1], (j & 3) << 4);
        mj[j] = (g2 ? vb : va) * (-1.0f / 128.0f);
    }
    __syncthreads();
    int4v aq1[4], aq2[4];
    {
        int r = wv * 32 + ln31;
        #pragma unroll
        for (int kc = 0; kc < 4; ++kc) {
            int c = kc * 2 + g2;
            aq1[kc] = *(const int4v*)&sB[r * 16 + (c ^ (r & 15))];
            aq2[kc] = *(const int4v*)&sB[r * 16 + ((8 + c) ^ (r & 15))];
        }
    }
    __syncthreads();

    // ---- stage B tile (g_cbi pre-swizzled -> fully linear copy) ----
    // 2 waves x 8 calls x 64 slots = 1024 uint4 slots (16 KB) per tile.
    #define STAGE_B(T, BUF)                                                     \
        _Pragma("unroll")                                                       \
        for (int jj = 0; jj < 8; ++jj) {                                        \
            int base = wv * 512 + jj * 64;                                      \
            __builtin_amdgcn_global_load_lds(                                   \
                (const void*)(g_cbi + (size_t)(T) * 1024 + base + lane),        \
                (void*)(sB + (BUF) * 1024 + base), 16, 0, 0);                   \
        }
    STAGE_B(0, 0)

    float m1[16], m2[16];
    int   i1[16];
    #pragma unroll
    for (int j = 0; j < 16; ++j) { m1[j] = 3.0e38f; m2[j] = 3.0e38f; i1[j] = 0; }

    float cn0 = cn[ln31], cn1 = cn[32 + ln31];
    float fc0 = g_scl[ln31], fc1 = g_scl[32 + ln31];
    const int x15 = ln31 & 15;

    for (int tile = 0; tile < VQ_K / 64; ++tile) {
        // stage for this tile issued a full iteration ago -> drain cheap
        asm volatile("s_waitcnt vmcnt(0)" ::: "memory");
        __builtin_amdgcn_s_barrier();
        __builtin_amdgcn_sched_barrier(0);

        const int bb = (tile & 1) << 10;     // current buffer base (uint4 slots)

        if (tile < VQ_K / 64 - 1) { STAGE_B(tile + 1, (tile + 1) & 1) }
        int nt = (tile + 1) & (VQ_K / 64 - 1);
        float ncn0 = cn[nt * 64 + ln31];
        float ncn1 = cn[nt * 64 + 32 + ln31];
        float nf0 = g_scl[nt * 64 + ln31];
        float nf1 = g_scl[nt * 64 + 32 + ln31];

        int kb = tile * 64 + ln31;

        // ================= half-pass 0: code column ln31 =================
        {
            i32x16 HH, XX;   // HH: q1z*q1c; XX: q1z*q2c + q2z*q1c (scale/256)
            #pragma unroll
            for (int j = 0; j < 16; ++j) { HH[j] = 0; XX[j] = 0; }

            __builtin_amdgcn_s_setprio(1);
            #pragma unroll
            for (int kc = 0; kc < 4; ++kc) {
                int c  = kc * 2 + g2;
                int p1 = c ^ x15, p2 = (8 + c) ^ x15;
                int4v bh = *(const int4v*)&sB[bb + ln31 * 16 + p1];
                int4v bl = *(const int4v*)&sB[bb + ln31 * 16 + p2];
                // integer accumulation -> order-exact; spread XX chain
                XX = __builtin_amdgcn_mfma_i32_32x32x32_i8(aq2[kc], bh, XX, 0, 0, 0);
                HH = __builtin_amdgcn_mfma_i32_32x32x32_i8(aq1[kc], bh, HH, 0, 0, 0);
                XX = __builtin_amdgcn_mfma_i32_32x32x32_i8(aq1[kc], bl, XX, 0, 0, 0);
            }
            __builtin_amdgcn_s_setprio(0);

            #pragma unroll
            for (int j = 0; j < 16; ++j) {
                float s0 = fmaf((float)((HH[j] << 8) + XX[j]) * fc0, mj[j], cn0);
                bool lt0 = s0 < m1[j];
                // m2' = median(s, m1, m2) == R13 semantics (m1 <= m2 invariant)
                m2[j] = fminf(fmaxf(s0, m1[j]), m2[j]);
                i1[j] = lt0 ? kb : i1[j];
                m1[j] = fminf(m1[j], s0);
            }
        }

        // ================= half-pass 1: code column 32+ln31 ==============
        {
            i32x16 HH, XX;
            #pragma unroll
            for (int j = 0; j < 16; ++j) { HH[j] = 0; XX[j] = 0; }

            __builtin_amdgcn_s_setprio(1);
            #pragma unroll
            for (int kc = 0; kc < 4; ++kc) {
                int c  = kc * 2 + g2;
                int p1 = c ^ x15, p2 = (8 + c) ^ x15;
                int4v bh = *(const int4v*)&sB[bb + (32 + ln31) * 16 + p1];
                int4v bl = *(const int4v*)&sB[bb + (32 + ln31) * 16 + p2];
                XX = __builtin_amdgcn_mfma_i32_32x32x32_i8(aq2[kc], bh, XX, 0, 0, 0);
                HH = __builtin_amdgcn_mfma_i32_32x32x32_i8(aq1[kc], bh, HH, 0, 0, 0);
                XX = __builtin_amdgcn_mfma_i32_32x32x32_i8(aq1[kc], bl, XX, 0, 0, 0);
            }
            __builtin_amdgcn_s_setprio(0);

            #pragma unroll
            for (int j = 0; j < 16; ++j) {
                float s1v = fmaf((float)((HH[j] << 8) + XX[j]) * fc1, mj[j], cn1);
                bool lt1 = s1v < m1[j];
                m2[j] = fminf(fmaxf(s1v, m1[j]), m2[j]);
                i1[j] = lt1 ? kb + 32 : i1[j];
                m1[j] = fminf(m1[j], s1v);
            }
        }

        cn0 = ncn0; cn1 = ncn1; fc0 = nf0; fc1 = nf1;
    }

    // ---- cross-lane top-2 merge over the 32-lane code groups (g2 fixed) ----
    #pragma unroll
    for (int j = 0; j < 16; ++j) {
        float a1v = m1[j], a2v = m2[j];
        int   ai  = i1[j];
        #pragma unroll
        for (int off = 1; off < 32; off <<= 1) {
            float o1 = __shfl_xor(a1v, off);
            float o2 = __shfl_xor(a2v, off);
            int   oi = __shfl_xor(ai, off);
            bool lt = o1 < a1v;
            float hi = lt ? a1v : o1;
            a1v = lt ? o1 : a1v;
            ai  = lt ? oi : ai;
            a2v = fminf(fminf(a2v, o2), hi);
            // exact inter-lane tie -> a2v==a1v -> flagged -> rescued
        }
        if (ln31 == 0) {
            int row = qb + wv * 32 + (j & 3) + 8 * (j >> 2) + 4 * g2;
            outIdx[row] = ai;
            if (a2v - a1v < VQ_THR) {
                g_res[row] = ~0ull;
                int pos = atomicAdd(&g_count, 1);
                g_list[pos] = row;
            }
        }
    }
    #undef STAGE_B
}

__global__ __launch_bounds__(256)
void vq_rescue(const float* __restrict__ ze,
               const float* __restrict__ cb,
               const float* __restrict__ cn) {
    __shared__ float cs[64 * 132];    // 64 codes x 128, padded +4
    __shared__ float zs[4][128];      // 4 flagged rows

    const int tid  = threadIdx.x;
    const int lane = tid & 63;
    const int wv   = tid >> 6;          // 0..3: one flagged row per wave
    const int count = g_count;
    const long nitems = (long)((count + 3) >> 2) * 32;

    for (long it = blockIdx.x; it < nitems; it += gridDim.x) {
        const int grp   = (int)(it >> 5);
        const int chunk = (int)(it & 31);
        const int slot  = grp * 4 + wv;
        const bool valid = slot < count;
        const int row = g_list[valid ? slot : (count - 1)];

        #pragma unroll
        for (int j = 0; j < 8; ++j) {
            int id = j * 256 + tid;
            int r = id >> 5, col = id & 31;
            float4 v = reinterpret_cast<const float4*>(cb)[(size_t)(chunk * 64 + r) * 32 + col];
            *reinterpret_cast<float4*>(&cs[r * 132 + col * 4]) = v;
        }
        if (tid < 128) {
            int w = tid >> 5, i = tid & 31;
            int s2 = grp * 4 + w; if (s2 >= count) s2 = count - 1;
            int rw = g_list[s2];
            float4 v = reinterpret_cast<const float4*>(ze)[(size_t)rw * 32 + i];
            *reinterpret_cast<float4*>(&zs[w][i * 4]) = v;
        }
        __syncthreads();

        if (valid) {
            float4 zn = {0.f, 0.f, 0.f, 0.f};
            #pragma unroll
            for (int i = 0; i < 32; ++i) {
                float4 z = *reinterpret_cast<const float4*>(&zs[wv][i * 4]);
                zn.x += z.x * z.x; zn.y += z.y * z.y;
                zn.z += z.z * z.z; zn.w += z.w * z.w;
            }
            float znorm = (zn.x + zn.y) + (zn.z + zn.w);

            int k = chunk * 64 + lane;
            float4 a = {0.f, 0.f, 0.f, 0.f};
            #pragma unroll
            for (int i = 0; i < 32; ++i) {
                float4 c = *reinterpret_cast<const float4*>(&cs[lane * 132 + i * 4]);
                float4 z = *reinterpret_cast<const float4*>(&zs[wv][i * 4]);
                a.x += z.x * c.x; a.y += z.y * c.y;
                a.z += z.z * c.z; a.w += z.w * c.w;
            }
            float dot = (a.x + a.y) + (a.z + a.w);
            float s = fmaf(-2.f, dot, znorm + cn[k]);

            u64 p = ((u64)__float_as_uint(s) << 32) | (unsigned)k;
            #pragma unroll
            for (int o = 1; o < 64; o <<= 1) {
                u64 q = __shfl_xor(p, o);
                p = q < p ? q : p;
            }
            if (lane == 0) atomicMin(&g_res[row], p);
        }
        __syncthreads();
    }
}

__global__ void vq_fix(int* __restrict__ outIdx) {
    int n = g_count;
    for (int i = blockIdx.x * 256 + threadIdx.x; i < n; i += gridDim.x * 256) {
        int row = g_list[i];
        outIdx[row] = (int)(g_res[row] & 0xFFFFFFFFull);
    }
}

__global__ void vq_gather(const float* __restrict__ cb,
                          const int* __restrict__ idx,
                          float* __restrict__ out) {
    size_t u = (size_t)blockIdx.x * blockDim.x + threadIdx.x;
    int r = (int)(u >> 5);
    int j = (int)(u & 31);
    reinterpret_cast<float4*>(out)[u] =
        reinterpret_cast<const float4*>(cb)[((size_t)idx[r] << 5) + j];
}

extern "C" void kernel_launch(void* const* d_in, const int* in_sizes, int n_in,
                              void* d_out, int out_size, void* d_ws, size_t ws_size,
                              hipStream_t stream) {
    const float* ze = (const float*)d_in[0];
    const float* cb = (const float*)d_in[1];
    float* out = (float*)d_out;

    float* cn   = (float*)d_ws;                        // 2048 f32 = 8 KB
    int*   bidx = (int*)((char*)d_ws + 8192);          // 65536 i32 = 256 KB

    vq_prepn<<<VQ_K * VQ_D / 8 / 256, 256, 0, stream>>>(cb, cn);
    vq_score<<<VQ_M / 64, 128, 0, stream>>>(ze, cn, bidx);
    vq_rescue<<<1024, 256, 0, stream>>>(ze, cb, cn);
    vq_fix<<<64, 256, 0, stream>>>(bidx);
    vq_gather<<<(VQ_M * (VQ_D / 4)) / 256, 256, 0, stream>>>(cb, bidx, out);
}

// Round 9
// 115.695 us; speedup vs baseline: 1.0695x; 1.0695x over previous
//
#include <hip/hip_runtime.h>
#include <hip/hip_bf16.h>

// VQ quantizer: ze [65536 x 128] f32, codebook [2048 x 128] f32.
// out[m,:] = codebook[argmin_k ||z_m - c_k||^2, :]
//
// Round 16: exact R13 structure (proven 88 us, absmax 0: 256 thr, 128
// rows/block, grid 512, 2 blocks/CU, i8 two-level MFMA, 32 acc regs) plus
// three work cuts:
//  (1) tile = 128 codes (16 iters): halves barrier/drain/loop overhead.
//      4 sequential 32-code column passes per tile; per-(row,code) MFMA
//      accumulation order bit-identical to R13; stream reorder only
//      affects exact ties, which are flagged (margin 0) and rescued.
//  (2) cn+scl fused into one float2 array (half the scalar loads).
//  (3) vq_fix folded into vq_gather (flag bit 31 in outIdx).
// Residency rule (R7-R15): total VGPR <= 128 -> 2 blocks/CU. THR 0.04.
//  vq_prepn:  codebook -> 2-level i8 (pre-swizzled); cs2[k]={||c||^2, s1c}.
//  vq_score:  i8 MFMA scores, streaming top-2, flag margin < THR.
//  vq_rescue: exact-fp32 rescan of flagged rows, deterministic first-index.
//  vq_gather: out = codebook[idx], rescued rows read g_res.

#define VQ_D 128
#define VQ_K 2048
#define VQ_M 65536
#define VQ_THR 0.04f

typedef short short8 __attribute__((ext_vector_type(8)));
typedef int  int4v  __attribute__((ext_vector_type(4)));
typedef int  i32x16 __attribute__((ext_vector_type(16)));
typedef unsigned long long u64;

// codebook, 2-level i8, pre-swizzled: row r = 16 chunks of 16B; logical
// chunk c (0-7 = level-1 bytes, 8-15 = level-2 bytes) stored at position
// c ^ (r&15). 512 KB total.
__device__ uint4 g_cbi[VQ_K * 16];
__device__ int   g_list[VQ_M];
__device__ u64   g_res[VQ_M];
__device__ int   g_count;

// prep: thread g handles 8 elems of row g>>4 (16 threads/row)
__global__ void vq_prepn(const float* __restrict__ cb, float2* __restrict__ cs2) {
    int g = blockIdx.x * 256 + threadIdx.x;          // 0..32767
    int r = g >> 4, t = g & 15;
    const float4* s = reinterpret_cast<const float4*>(cb) + (size_t)g * 2;
    float4 f0 = s[0], f1 = s[1];
    float z[8] = {f0.x, f0.y, f0.z, f0.w, f1.x, f1.y, f1.z, f1.w};
    float ss = ((z[0]*z[0] + z[1]*z[1]) + (z[2]*z[2] + z[3]*z[3]))
             + ((z[4]*z[4] + z[5]*z[5]) + (z[6]*z[6] + z[7]*z[7]));
    float ax = fmaxf(fmaxf(fmaxf(fabsf(z[0]), fabsf(z[1])), fmaxf(fabsf(z[2]), fabsf(z[3]))),
                     fmaxf(fmaxf(fabsf(z[4]), fabsf(z[5])), fmaxf(fabsf(z[6]), fabsf(z[7]))));
    ss += __shfl_xor(ss, 1); ax = fmaxf(ax, __shfl_xor(ax, 1));
    ss += __shfl_xor(ss, 2); ax = fmaxf(ax, __shfl_xor(ax, 2));
    ss += __shfl_xor(ss, 4); ax = fmaxf(ax, __shfl_xor(ax, 4));
    ss += __shfl_xor(ss, 8); ax = fmaxf(ax, __shfl_xor(ax, 8));
    float mx  = fmaxf(ax, 1e-20f);
    float s1  = mx * (1.0f / 127.0f);
    float inv = 127.0f / mx;
    float inv2 = inv * 256.0f;
    int qa[8], qr[8];
    #pragma unroll
    for (int i = 0; i < 8; ++i) {
        float qf = rintf(z[i] * inv);
        float r1 = fmaf(-qf, s1, z[i]);
        float q2f = fminf(127.f, fmaxf(-127.f, rintf(r1 * inv2)));
        qa[i] = (int)qf; qr[i] = (int)q2f;
    }
    uint2 w1, w2;
    w1.x = (qa[0]&255) | ((qa[1]&255)<<8) | ((qa[2]&255)<<16) | ((unsigned)(qa[3]&255)<<24);
    w1.y = (qa[4]&255) | ((qa[5]&255)<<8) | ((qa[6]&255)<<16) | ((unsigned)(qa[7]&255)<<24);
    w2.x = (qr[0]&255) | ((qr[1]&255)<<8) | ((qr[2]&255)<<16) | ((unsigned)(qr[3]&255)<<24);
    w2.y = (qr[4]&255) | ((qr[5]&255)<<8) | ((qr[6]&255)<<16) | ((unsigned)(qr[7]&255)<<24);
    uint2* cw = reinterpret_cast<uint2*>(g_cbi);
    int c1 = (t >> 1) ^ (r & 15);
    int c2 = (8 + (t >> 1)) ^ (r & 15);
    cw[(r * 16 + c1) * 2 + (t & 1)] = w1;
    cw[(r * 16 + c2) * 2 + (t & 1)] = w2;
    if (t == 0) cs2[r] = make_float2(ss, s1);
    if (g == 0) g_count = 0;
}

__global__ __launch_bounds__(256, 2)
void vq_score(const float* __restrict__ ze,
              const float2* __restrict__ cs2,
              int* __restrict__ outIdx) {
    __shared__ uint4 sB[4096];   // 64 KB: prologue A staging (first 32 KB);
                                 // main loop: dbuf 128-code B tile (2 x 32 KB).
    const int tid  = threadIdx.x;
    const int lane = tid & 63;
    const int wv   = tid >> 6;          // 0..3, wave owns 32 query rows
    const int ln31 = lane & 31;
    const int g2   = lane >> 5;         // 0/1: k-half selector
    const int qb   = blockIdx.x * 128;

    // ---- prologue: 2-level i8 quantize; rows are WAVE-OWNED:
    //      id = wv*512 + jj*64 + lane -> row r = wv*32 + jj*4 + (lane>>4)
    uint2 q1w[8], q2w[8];
    float s1r[8];                       // this lane's 16-group row scale, per jj
    #pragma unroll
    for (int jj = 0; jj < 8; ++jj) {
        int id = wv * 512 + jj * 64 + lane, r = id >> 4, t = id & 15;
        const float4* src =
            reinterpret_cast<const float4*>(ze + (size_t)(qb + r) * VQ_D + t * 8);
        float4 f0 = src[0], f1 = src[1];
        float z[8] = {f0.x, f0.y, f0.z, f0.w, f1.x, f1.y, f1.z, f1.w};
        float ax = fmaxf(fmaxf(fmaxf(fabsf(z[0]), fabsf(z[1])), fmaxf(fabsf(z[2]), fabsf(z[3]))),
                         fmaxf(fmaxf(fabsf(z[4]), fabsf(z[5])), fmaxf(fabsf(z[6]), fabsf(z[7]))));
        ax = fmaxf(ax, __shfl_xor(ax, 1));
        ax = fmaxf(ax, __shfl_xor(ax, 2));
        ax = fmaxf(ax, __shfl_xor(ax, 4));
        ax = fmaxf(ax, __shfl_xor(ax, 8));
        float mx  = fmaxf(ax, 1e-20f);
        float s1  = mx * (1.0f / 127.0f);
        float inv = 127.0f / mx;
        float inv2 = inv * 256.0f;
        s1r[jj] = s1;
        int qa[8], qr[8];
        #pragma unroll
        for (int i = 0; i < 8; ++i) {
            float qf = rintf(z[i] * inv);
            float r1 = fmaf(-qf, s1, z[i]);
            float q2f = fminf(127.f, fmaxf(-127.f, rintf(r1 * inv2)));
            qa[i] = (int)qf; qr[i] = (int)q2f;
        }
        q1w[jj].x = (qa[0]&255) | ((qa[1]&255)<<8) | ((qa[2]&255)<<16) | ((unsigned)(qa[3]&255)<<24);
        q1w[jj].y = (qa[4]&255) | ((qa[5]&255)<<8) | ((qa[6]&255)<<16) | ((unsigned)(qa[7]&255)<<24);
        q2w[jj].x = (qr[0]&255) | ((qr[1]&255)<<8) | ((qr[2]&255)<<16) | ((unsigned)(qr[3]&255)<<24);
        q2w[jj].y = (qr[4]&255) | ((qr[5]&255)<<8) | ((qr[6]&255)<<16) | ((unsigned)(qr[7]&255)<<24);
    }
    {
        uint2* sw = reinterpret_cast<uint2*>(sB);
        #pragma unroll
        for (int jj = 0; jj < 8; ++jj) {
            int id = wv * 512 + jj * 64 + lane, r = id >> 4, t = id & 15;
            int c1 = (t >> 1) ^ (r & 15);
            int c2 = (8 + (t >> 1)) ^ (r & 15);
            sw[(r * 16 + c1) * 2 + (t & 1)] = q1w[jj];
            sw[(r * 16 + c2) * 2 + (t & 1)] = q2w[jj];
        }
    }
    // per-row scale -> mj[j] via shfl (row rl = (j&3)+8*(j>>2)+4*g2;
    // held by lanes (rl&3)*16.. in s1r[rl>>2]; rl>>2 = 2*(j>>2)+g2)
    float mj[16];
    #pragma unroll
    for (int j = 0; j < 16; ++j) {
        float va = __shfl(s1r[2 * (j >> 2)],     (j & 3) << 4);
        float vb = __shfl(s1r[2 * (j >> 2) + 1], (j & 3) << 4);
        mj[j] = (g2 ? vb : va) * (-1.0f / 128.0f);
    }
    __syncthreads();
    int4v aq1[4], aq2[4];
    {
        int r = wv * 32 + ln31;
        #pragma unroll
        for (int kc = 0; kc < 4; ++kc) {
            int c = kc * 2 + g2;
            aq1[kc] = *(const int4v*)&sB[r * 16 + (c ^ (r & 15))];
            aq2[kc] = *(const int4v*)&sB[r * 16 + ((8 + c) ^ (r & 15))];
        }
    }
    __syncthreads();

    // ---- stage 128-code B tile (pre-swizzled -> fully linear copy) ----
    // 2048 uint4 slots per tile; 8 rounds x 256 threads x 16B.
    #define STAGE_B(T, BUF)                                                     \
        _Pragma("unroll")                                                       \
        for (int jj = 0; jj < 8; ++jj) {                                        \
            int base = wv * 512 + jj * 64;                                      \
            __builtin_amdgcn_global_load_lds(                                   \
                (const void*)(g_cbi + (size_t)(T) * 2048 + base + lane),        \
                (void*)(sB + (BUF) * 2048 + base), 16, 0, 0);                   \
        }
    STAGE_B(0, 0)

    float m1[16], m2[16];
    int   i1[16];
    #pragma unroll
    for (int j = 0; j < 16; ++j) { m1[j] = 3.0e38f; m2[j] = 3.0e38f; i1[j] = 0; }

    const int x15 = ln31 & 15;

    for (int tile = 0; tile < VQ_K / 128; ++tile) {
        // stage for this tile issued a full iteration ago -> drain cheap
        asm volatile("s_waitcnt vmcnt(0)" ::: "memory");
        __builtin_amdgcn_s_barrier();
        __builtin_amdgcn_sched_barrier(0);

        const int bb = (tile & 1) << 11;     // current buffer base (uint4 slots)

        if (tile < VQ_K / 128 - 1) { STAGE_B(tile + 1, (tile + 1) & 1) }

        // ---- 4 column passes: codes tile*128 + col*32 + ln31 ----
        #pragma unroll
        for (int col = 0; col < 4; ++col) {
            const int cr = col * 32 + ln31;            // B row in tile
            const int kb = tile * 128 + cr;            // global code id
            float2 cf = cs2[kb];                       // {||c||^2, s1c} (early issue)

            i32x16 HH, XX;   // HH: q1z*q1c; XX: q1z*q2c + q2z*q1c (scale/256)
            #pragma unroll
            for (int j = 0; j < 16; ++j) { HH[j] = 0; XX[j] = 0; }

            __builtin_amdgcn_s_setprio(1);
            #pragma unroll
            for (int kc = 0; kc < 4; ++kc) {
                int c  = kc * 2 + g2;
                int p1 = c ^ x15, p2 = (8 + c) ^ x15;
                int4v bh = *(const int4v*)&sB[bb + cr * 16 + p1];
                int4v bl = *(const int4v*)&sB[bb + cr * 16 + p2];
                // integer accumulation -> order-exact; spread XX chain
                XX = __builtin_amdgcn_mfma_i32_32x32x32_i8(aq2[kc], bh, XX, 0, 0, 0);
                HH = __builtin_amdgcn_mfma_i32_32x32x32_i8(aq1[kc], bh, HH, 0, 0, 0);
                XX = __builtin_amdgcn_mfma_i32_32x32x32_i8(aq1[kc], bl, XX, 0, 0, 0);
            }
            __builtin_amdgcn_s_setprio(0);

            #pragma unroll
            for (int j = 0; j < 16; ++j) {
                float s0 = fmaf((float)((HH[j] << 8) + XX[j]) * cf.y, mj[j], cf.x);
                bool lt0 = s0 < m1[j];
                m2[j] = lt0 ? m1[j] : fminf(m2[j], s0);
                i1[j] = lt0 ? kb : i1[j];
                m1[j] = lt0 ? s0 : m1[j];
            }
        }
    }

    // ---- cross-lane top-2 merge over the 32-lane code groups (g2 fixed) ----
    #pragma unroll
    for (int j = 0; j < 16; ++j) {
        float a1v = m1[j], a2v = m2[j];
        int   ai  = i1[j];
        #pragma unroll
        for (int off = 1; off < 32; off <<= 1) {
            float o1 = __shfl_xor(a1v, off);
            float o2 = __shfl_xor(a2v, off);
            int   oi = __shfl_xor(ai, off);
            bool lt = o1 < a1v;
            float hi = lt ? a1v : o1;
            a1v = lt ? o1 : a1v;
            ai  = lt ? oi : ai;
            a2v = fminf(fminf(a2v, o2), hi);
            // exact inter-lane tie -> a2v==a1v -> flagged -> rescued
        }
        if (ln31 == 0) {
            int row = qb + wv * 32 + (j & 3) + 8 * (j >> 2) + 4 * g2;
            if (a2v - a1v < VQ_THR) {
                outIdx[row] = (int)((unsigned)ai | 0x80000000u);   // flag bit 31
                g_res[row] = ~0ull;
                int pos = atomicAdd(&g_count, 1);
                g_list[pos] = row;
            } else {
                outIdx[row] = ai;
            }
        }
    }
    #undef STAGE_B
}

__global__ __launch_bounds__(256)
void vq_rescue(const float* __restrict__ ze,
               const float* __restrict__ cb,
               const float2* __restrict__ cs2) {
    __shared__ float cs[64 * 132];    // 64 codes x 128, padded +4
    __shared__ float zs[4][128];      // 4 flagged rows

    const int tid  = threadIdx.x;
    const int lane = tid & 63;
    const int wv   = tid >> 6;          // 0..3: one flagged row per wave
    const int count = g_count;
    const long nitems = (long)((count + 3) >> 2) * 32;

    for (long it = blockIdx.x; it < nitems; it += gridDim.x) {
        const int grp   = (int)(it >> 5);
        const int chunk = (int)(it & 31);
        const int slot  = grp * 4 + wv;
        const bool valid = slot < count;
        const int row = g_list[valid ? slot : (count - 1)];

        #pragma unroll
        for (int j = 0; j < 8; ++j) {
            int id = j * 256 + tid;
            int r = id >> 5, col = id & 31;
            float4 v = reinterpret_cast<const float4*>(cb)[(size_t)(chunk * 64 + r) * 32 + col];
            *reinterpret_cast<float4*>(&cs[r * 132 + col * 4]) = v;
        }
        if (tid < 128) {
            int w = tid >> 5, i = tid & 31;
            int s2 = grp * 4 + w; if (s2 >= count) s2 = count - 1;
            int rw = g_list[s2];
            float4 v = reinterpret_cast<const float4*>(ze)[(size_t)rw * 32 + i];
            *reinterpret_cast<float4*>(&zs[w][i * 4]) = v;
        }
        __syncthreads();

        if (valid) {
            float4 zn = {0.f, 0.f, 0.f, 0.f};
            #pragma unroll
            for (int i = 0; i < 32; ++i) {
                float4 z = *reinterpret_cast<const float4*>(&zs[wv][i * 4]);
                zn.x += z.x * z.x; zn.y += z.y * z.y;
                zn.z += z.z * z.z; zn.w += z.w * z.w;
            }
            float znorm = (zn.x + zn.y) + (zn.z + zn.w);

            int k = chunk * 64 + lane;
            float4 a = {0.f, 0.f, 0.f, 0.f};
            #pragma unroll
            for (int i = 0; i < 32; ++i) {
                float4 c = *reinterpret_cast<const float4*>(&cs[lane * 132 + i * 4]);
                float4 z = *reinterpret_cast<const float4*>(&zs[wv][i * 4]);
                a.x += z.x * c.x; a.y += z.y * c.y;
                a.z += z.z * c.z; a.w += z.w * c.w;
            }
            float dot = (a.x + a.y) + (a.z + a.w);
            float s = fmaf(-2.f, dot, znorm + cs2[k].x);

            u64 p = ((u64)__float_as_uint(s) << 32) | (unsigned)k;
            #pragma unroll
            for (int o = 1; o < 64; o <<= 1) {
                u64 q = __shfl_xor(p, o);
                p = q < p ? q : p;
            }
            if (lane == 0) atomicMin(&g_res[row], p);
        }
        __syncthreads();
    }
}

// gather with fused fix: flagged rows (bit 31) read the rescued index.
__global__ void vq_gather(const float* __restrict__ cb,
                          const int* __restrict__ idx,
                          float* __restrict__ out) {
    size_t u = (size_t)blockIdx.x * blockDim.x + threadIdx.x;
    int r = (int)(u >> 5);
    int j = (int)(u & 31);
    int v = idx[r];
    if (v < 0) v = (int)(g_res[r] & 0xFFFFFFFFull);
    reinterpret_cast<float4*>(out)[u] =
        reinterpret_cast<const float4*>(cb)[((size_t)v << 5) + j];
}

extern "C" void kernel_launch(void* const* d_in, const int* in_sizes, int n_in,
                              void* d_out, int out_size, void* d_ws, size_t ws_size,
                              hipStream_t stream) {
    const float* ze = (const float*)d_in[0];
    const float* cb = (const float*)d_in[1];
    float* out = (float*)d_out;

    float2* cs2  = (float2*)d_ws;                      // 2048 float2 = 16 KB
    int*    bidx = (int*)((char*)d_ws + 16384);        // 65536 i32 = 256 KB

    vq_prepn<<<VQ_K * VQ_D / 8 / 256, 256, 0, stream>>>(cb, cs2);
    vq_score<<<VQ_M / 128, 256, 0, stream>>>(ze, cs2, bidx);
    vq_rescue<<<1024, 256, 0, stream>>>(ze, cb, cs2);
    vq_gather<<<(VQ_M * (VQ_D / 4)) / 256, 256, 0, stream>>>(cb, bidx, out);
}

// Round 10
// 112.597 us; speedup vs baseline: 1.0989x; 1.0275x over previous
//
#include <hip/hip_runtime.h>
#include <hip/hip_bf16.h>

// VQ quantizer: ze [65536 x 128] f32, codebook [2048 x 128] f32.
// out[m,:] = codebook[argmin_k ||z_m - c_k||^2, :]
//
// Round 17: R13 structure exactly (proven 88 us, absmax 0: 256 thr, 128
// rows/block, grid 512, 2 blocks/CU, i8 two-level MFMA, two half-passes,
// 32 acc regs) + VALU work cuts:
//  (1) m2 update via v_med3_f32 (__builtin_amdgcn_fmed3f): 1 inst replaces
//      cmp+fmin+cndmask. Exact same result under the m1<=m2 invariant.
//  (2) shared zero vector Z as C-operand of each half-pass's first MFMAs
//      (D != C is legal): kills 32 v_mov acc-init per half-pass.
//  (3) cn+scl fused as float2 cs2[] with R13's full-tile prefetch distance
//      (R16's in-loop load was the regression; prefetch fixes it).
//  (4) vq_fix folded into vq_gather (flag bit 31), from R16 (proven).
// Residency model (9 pts): pool 512/SIMD, wave = rup64(arch)+rup64(acc);
// keep arch <= 128 -> 2 blocks/CU. THR 0.04.
//  vq_prepn:  codebook -> 2-level i8 (pre-swizzled); cs2[k]={||c||^2, s1c}.
//  vq_score:  i8 MFMA scores, streaming top-2, flag margin < THR.
//  vq_rescue: exact-fp32 rescan of flagged rows, deterministic first-index.
//  vq_gather: out = codebook[idx], rescued rows read g_res.

#define VQ_D 128
#define VQ_K 2048
#define VQ_M 65536
#define VQ_THR 0.04f

typedef short short8 __attribute__((ext_vector_type(8)));
typedef int  int4v  __attribute__((ext_vector_type(4)));
typedef int  i32x16 __attribute__((ext_vector_type(16)));
typedef unsigned long long u64;

// codebook, 2-level i8, pre-swizzled: row r = 16 chunks of 16B; logical
// chunk c (0-7 = level-1 bytes, 8-15 = level-2 bytes) stored at position
// c ^ (r&15). 512 KB total.
__device__ uint4 g_cbi[VQ_K * 16];
__device__ int   g_list[VQ_M];
__device__ u64   g_res[VQ_M];
__device__ int   g_count;

// prep: thread g handles 8 elems of row g>>4 (16 threads/row)
__global__ void vq_prepn(const float* __restrict__ cb, float2* __restrict__ cs2) {
    int g = blockIdx.x * 256 + threadIdx.x;          // 0..32767
    int r = g >> 4, t = g & 15;
    const float4* s = reinterpret_cast<const float4*>(cb) + (size_t)g * 2;
    float4 f0 = s[0], f1 = s[1];
    float z[8] = {f0.x, f0.y, f0.z, f0.w, f1.x, f1.y, f1.z, f1.w};
    float ss = ((z[0]*z[0] + z[1]*z[1]) + (z[2]*z[2] + z[3]*z[3]))
             + ((z[4]*z[4] + z[5]*z[5]) + (z[6]*z[6] + z[7]*z[7]));
    float ax = fmaxf(fmaxf(fmaxf(fabsf(z[0]), fabsf(z[1])), fmaxf(fabsf(z[2]), fabsf(z[3]))),
                     fmaxf(fmaxf(fabsf(z[4]), fabsf(z[5])), fmaxf(fabsf(z[6]), fabsf(z[7]))));
    ss += __shfl_xor(ss, 1); ax = fmaxf(ax, __shfl_xor(ax, 1));
    ss += __shfl_xor(ss, 2); ax = fmaxf(ax, __shfl_xor(ax, 2));
    ss += __shfl_xor(ss, 4); ax = fmaxf(ax, __shfl_xor(ax, 4));
    ss += __shfl_xor(ss, 8); ax = fmaxf(ax, __shfl_xor(ax, 8));
    float mx  = fmaxf(ax, 1e-20f);
    float s1  = mx * (1.0f / 127.0f);
    float inv = 127.0f / mx;
    float inv2 = inv * 256.0f;
    int qa[8], qr[8];
    #pragma unroll
    for (int i = 0; i < 8; ++i) {
        float qf = rintf(z[i] * inv);
        float r1 = fmaf(-qf, s1, z[i]);
        float q2f = fminf(127.f, fmaxf(-127.f, rintf(r1 * inv2)));
        qa[i] = (int)qf; qr[i] = (int)q2f;
    }
    uint2 w1, w2;
    w1.x = (qa[0]&255) | ((qa[1]&255)<<8) | ((qa[2]&255)<<16) | ((unsigned)(qa[3]&255)<<24);
    w1.y = (qa[4]&255) | ((qa[5]&255)<<8) | ((qa[6]&255)<<16) | ((unsigned)(qa[7]&255)<<24);
    w2.x = (qr[0]&255) | ((qr[1]&255)<<8) | ((qr[2]&255)<<16) | ((unsigned)(qr[3]&255)<<24);
    w2.y = (qr[4]&255) | ((qr[5]&255)<<8) | ((qr[6]&255)<<16) | ((unsigned)(qr[7]&255)<<24);
    uint2* cw = reinterpret_cast<uint2*>(g_cbi);
    int c1 = (t >> 1) ^ (r & 15);
    int c2 = (8 + (t >> 1)) ^ (r & 15);
    cw[(r * 16 + c1) * 2 + (t & 1)] = w1;
    cw[(r * 16 + c2) * 2 + (t & 1)] = w2;
    if (t == 0) cs2[r] = make_float2(ss, s1);
    if (g == 0) g_count = 0;
}

__global__ __launch_bounds__(256, 2)
void vq_score(const float* __restrict__ ze,
              const float2* __restrict__ cs2,
              int* __restrict__ outIdx) {
    __shared__ uint4 sB[2048];   // 32 KB exactly: prologue A staging;
                                 // main loop: double-buffered B tile (2 x 16 KB).
    const int tid  = threadIdx.x;
    const int lane = tid & 63;
    const int wv   = tid >> 6;          // 0..3, wave owns 32 query rows
    const int ln31 = lane & 31;
    const int g2   = lane >> 5;         // 0/1: k-half selector
    const int qb   = blockIdx.x * 128;

    // ---- prologue: 2-level i8 quantize; rows are WAVE-OWNED:
    //      id = wv*512 + jj*64 + lane -> row r = wv*32 + jj*4 + (lane>>4)
    uint2 q1w[8], q2w[8];
    float s1r[8];                       // this lane's 16-group row scale, per jj
    #pragma unroll
    for (int jj = 0; jj < 8; ++jj) {
        int id = wv * 512 + jj * 64 + lane, r = id >> 4, t = id & 15;
        const float4* src =
            reinterpret_cast<const float4*>(ze + (size_t)(qb + r) * VQ_D + t * 8);
        float4 f0 = src[0], f1 = src[1];
        float z[8] = {f0.x, f0.y, f0.z, f0.w, f1.x, f1.y, f1.z, f1.w};
        float ax = fmaxf(fmaxf(fmaxf(fabsf(z[0]), fabsf(z[1])), fmaxf(fabsf(z[2]), fabsf(z[3]))),
                         fmaxf(fmaxf(fabsf(z[4]), fabsf(z[5])), fmaxf(fabsf(z[6]), fabsf(z[7]))));
        ax = fmaxf(ax, __shfl_xor(ax, 1));
        ax = fmaxf(ax, __shfl_xor(ax, 2));
        ax = fmaxf(ax, __shfl_xor(ax, 4));
        ax = fmaxf(ax, __shfl_xor(ax, 8));
        float mx  = fmaxf(ax, 1e-20f);
        float s1  = mx * (1.0f / 127.0f);
        float inv = 127.0f / mx;
        float inv2 = inv * 256.0f;
        s1r[jj] = s1;
        int qa[8], qr[8];
        #pragma unroll
        for (int i = 0; i < 8; ++i) {
            float qf = rintf(z[i] * inv);
            float r1 = fmaf(-qf, s1, z[i]);
            float q2f = fminf(127.f, fmaxf(-127.f, rintf(r1 * inv2)));
            qa[i] = (int)qf; qr[i] = (int)q2f;
        }
        q1w[jj].x = (qa[0]&255) | ((qa[1]&255)<<8) | ((qa[2]&255)<<16) | ((unsigned)(qa[3]&255)<<24);
        q1w[jj].y = (qa[4]&255) | ((qa[5]&255)<<8) | ((qa[6]&255)<<16) | ((unsigned)(qa[7]&255)<<24);
        q2w[jj].x = (qr[0]&255) | ((qr[1]&255)<<8) | ((qr[2]&255)<<16) | ((unsigned)(qr[3]&255)<<24);
        q2w[jj].y = (qr[4]&255) | ((qr[5]&255)<<8) | ((qr[6]&255)<<16) | ((unsigned)(qr[7]&255)<<24);
    }
    {
        uint2* sw = reinterpret_cast<uint2*>(sB);
        #pragma unroll
        for (int jj = 0; jj < 8; ++jj) {
            int id = wv * 512 + jj * 64 + lane, r = id >> 4, t = id & 15;
            int c1 = (t >> 1) ^ (r & 15);
            int c2 = (8 + (t >> 1)) ^ (r & 15);
            sw[(r * 16 + c1) * 2 + (t & 1)] = q1w[jj];
            sw[(r * 16 + c2) * 2 + (t & 1)] = q2w[jj];
        }
    }
    // per-row scale -> mj[j] via shfl (row rl = (j&3)+8*(j>>2)+4*g2;
    // held by lanes (rl&3)*16.. in s1r[rl>>2]; rl>>2 = 2*(j>>2)+g2)
    float mj[16];
    #pragma unroll
    for (int j = 0; j < 16; ++j) {
        float va = __shfl(s1r[2 * (j >> 2)],     (j & 3) << 4);
        float vb = __shfl(s1r[2 * (j >> 2) + 1], (j & 3) << 4);
        mj[j] = (g2 ? vb : va) * (-1.0f / 128.0f);
    }
    __syncthreads();
    int4v aq1[4], aq2[4];
    {
        int r = wv * 32 + ln31;
        #pragma unroll
        for (int kc = 0; kc < 4; ++kc) {
            int c = kc * 2 + g2;
            aq1[kc] = *(const int4v*)&sB[r * 16 + (c ^ (r & 15))];
            aq2[kc] = *(const int4v*)&sB[r * 16 + ((8 + c) ^ (r & 15))];
        }
    }
    __syncthreads();

    // ---- stage B tile (g_cbi pre-swizzled -> fully linear copy) ----
    #define STAGE_B(T, BUF)                                                     \
        _Pragma("unroll")                                                       \
        for (int jj = 0; jj < 4; ++jj) {                                        \
            int base = wv * 256 + jj * 64;                                      \
            __builtin_amdgcn_global_load_lds(                                   \
                (const void*)(g_cbi + (size_t)(T) * 1024 + base + lane),        \
                (void*)(sB + (BUF) * 1024 + base), 16, 0, 0);                   \
        }
    STAGE_B(0, 0)

    float m1[16], m2[16];
    int   i1[16];
    #pragma unroll
    for (int j = 0; j < 16; ++j) { m1[j] = 3.0e38f; m2[j] = 3.0e38f; i1[j] = 0; }

    // shared zero accumulator: C-operand of each half-pass's first MFMAs
    i32x16 Z;
    #pragma unroll
    for (int j = 0; j < 16; ++j) Z[j] = 0;

    float2 cf0 = cs2[ln31];
    float2 cf1 = cs2[32 + ln31];
    const int x15 = ln31 & 15;

    for (int tile = 0; tile < VQ_K / 64; ++tile) {
        // stage for this tile issued a full iteration ago -> drain cheap
        asm volatile("s_waitcnt vmcnt(0)" ::: "memory");
        __builtin_amdgcn_s_barrier();
        __builtin_amdgcn_sched_barrier(0);

        const int bb = (tile & 1) << 10;     // current buffer base (uint4 slots)

        if (tile < VQ_K / 64 - 1) { STAGE_B(tile + 1, (tile + 1) & 1) }
        int nt = (tile + 1) & (VQ_K / 64 - 1);
        float2 nf0 = cs2[nt * 64 + ln31];          // full-tile prefetch distance
        float2 nf1 = cs2[nt * 64 + 32 + ln31];

        int kb = tile * 64 + ln31;

        // ================= half-pass 0: code column ln31 =================
        {
            i32x16 HH, XX;   // HH: q1z*q1c; XX: q1z*q2c + q2z*q1c (scale/256)
            __builtin_amdgcn_s_setprio(1);
            {   // kc = 0 peeled: C-in = Z (no acc zero-init movs)
                int c  = g2;
                int p1 = c ^ x15, p2 = (8 + c) ^ x15;
                int4v bh = *(const int4v*)&sB[bb + ln31 * 16 + p1];
                int4v bl = *(const int4v*)&sB[bb + ln31 * 16 + p2];
                XX = __builtin_amdgcn_mfma_i32_32x32x32_i8(aq2[0], bh, Z, 0, 0, 0);
                HH = __builtin_amdgcn_mfma_i32_32x32x32_i8(aq1[0], bh, Z, 0, 0, 0);
                XX = __builtin_amdgcn_mfma_i32_32x32x32_i8(aq1[0], bl, XX, 0, 0, 0);
            }
            #pragma unroll
            for (int kc = 1; kc < 4; ++kc) {
                int c  = kc * 2 + g2;
                int p1 = c ^ x15, p2 = (8 + c) ^ x15;
                int4v bh = *(const int4v*)&sB[bb + ln31 * 16 + p1];
                int4v bl = *(const int4v*)&sB[bb + ln31 * 16 + p2];
                // integer accumulation -> order-exact; spread XX chain
                XX = __builtin_amdgcn_mfma_i32_32x32x32_i8(aq2[kc], bh, XX, 0, 0, 0);
                HH = __builtin_amdgcn_mfma_i32_32x32x32_i8(aq1[kc], bh, HH, 0, 0, 0);
                XX = __builtin_amdgcn_mfma_i32_32x32x32_i8(aq1[kc], bl, XX, 0, 0, 0);
            }
            __builtin_amdgcn_s_setprio(0);

            #pragma unroll
            for (int j = 0; j < 16; ++j) {
                float s0 = fmaf((float)((HH[j] << 8) + XX[j]) * cf0.y, mj[j], cf0.x);
                bool lt0 = s0 < m1[j];
                m2[j] = __builtin_amdgcn_fmed3f(s0, m1[j], m2[j]);
                i1[j] = lt0 ? kb : i1[j];
                m1[j] = fminf(m1[j], s0);
            }
        }

        // ================= half-pass 1: code column 32+ln31 ==============
        {
            i32x16 HH, XX;
            __builtin_amdgcn_s_setprio(1);
            {   // kc = 0 peeled: C-in = Z
                int c  = g2;
                int p1 = c ^ x15, p2 = (8 + c) ^ x15;
                int4v bh = *(const int4v*)&sB[bb + (32 + ln31) * 16 + p1];
                int4v bl = *(const int4v*)&sB[bb + (32 + ln31) * 16 + p2];
                XX = __builtin_amdgcn_mfma_i32_32x32x32_i8(aq2[0], bh, Z, 0, 0, 0);
                HH = __builtin_amdgcn_mfma_i32_32x32x32_i8(aq1[0], bh, Z, 0, 0, 0);
                XX = __builtin_amdgcn_mfma_i32_32x32x32_i8(aq1[0], bl, XX, 0, 0, 0);
            }
            #pragma unroll
            for (int kc = 1; kc < 4; ++kc) {
                int c  = kc * 2 + g2;
                int p1 = c ^ x15, p2 = (8 + c) ^ x15;
                int4v bh = *(const int4v*)&sB[bb + (32 + ln31) * 16 + p1];
                int4v bl = *(const int4v*)&sB[bb + (32 + ln31) * 16 + p2];
                XX = __builtin_amdgcn_mfma_i32_32x32x32_i8(aq2[kc], bh, XX, 0, 0, 0);
                HH = __builtin_amdgcn_mfma_i32_32x32x32_i8(aq1[kc], bh, HH, 0, 0, 0);
                XX = __builtin_amdgcn_mfma_i32_32x32x32_i8(aq1[kc], bl, XX, 0, 0, 0);
            }
            __builtin_amdgcn_s_setprio(0);

            #pragma unroll
            for (int j = 0; j < 16; ++j) {
                float s1v = fmaf((float)((HH[j] << 8) + XX[j]) * cf1.y, mj[j], cf1.x);
                bool lt1 = s1v < m1[j];
                m2[j] = __builtin_amdgcn_fmed3f(s1v, m1[j], m2[j]);
                i1[j] = lt1 ? kb + 32 : i1[j];
                m1[j] = fminf(m1[j], s1v);
            }
        }

        cf0 = nf0; cf1 = nf1;
    }

    // ---- cross-lane top-2 merge over the 32-lane code groups (g2 fixed) ----
    #pragma unroll
    for (int j = 0; j < 16; ++j) {
        float a1v = m1[j], a2v = m2[j];
        int   ai  = i1[j];
        #pragma unroll
        for (int off = 1; off < 32; off <<= 1) {
            float o1 = __shfl_xor(a1v, off);
            float o2 = __shfl_xor(a2v, off);
            int   oi = __shfl_xor(ai, off);
            bool lt = o1 < a1v;
            float hi = lt ? a1v : o1;
            a1v = lt ? o1 : a1v;
            ai  = lt ? oi : ai;
            a2v = fminf(fminf(a2v, o2), hi);
            // exact inter-lane tie -> a2v==a1v -> flagged -> rescued
        }
        if (ln31 == 0) {
            int row = qb + wv * 32 + (j & 3) + 8 * (j >> 2) + 4 * g2;
            if (a2v - a1v < VQ_THR) {
                outIdx[row] = (int)((unsigned)ai | 0x80000000u);   // flag bit 31
                g_res[row] = ~0ull;
                int pos = atomicAdd(&g_count, 1);
                g_list[pos] = row;
            } else {
                outIdx[row] = ai;
            }
        }
    }
    #undef STAGE_B
}

__global__ __launch_bounds__(256)
void vq_rescue(const float* __restrict__ ze,
               const float* __restrict__ cb,
               const float2* __restrict__ cs2) {
    __shared__ float cs[64 * 132];    // 64 codes x 128, padded +4
    __shared__ float zs[4][128];      // 4 flagged rows

    const int tid  = threadIdx.x;
    const int lane = tid & 63;
    const int wv   = tid >> 6;          // 0..3: one flagged row per wave
    const int count = g_count;
    const long nitems = (long)((count + 3) >> 2) * 32;

    for (long it = blockIdx.x; it < nitems; it += gridDim.x) {
        const int grp   = (int)(it >> 5);
        const int chunk = (int)(it & 31);
        const int slot  = grp * 4 + wv;
        const bool valid = slot < count;
        const int row = g_list[valid ? slot : (count - 1)];

        #pragma unroll
        for (int j = 0; j < 8; ++j) {
            int id = j * 256 + tid;
            int r = id >> 5, col = id & 31;
            float4 v = reinterpret_cast<const float4*>(cb)[(size_t)(chunk * 64 + r) * 32 + col];
            *reinterpret_cast<float4*>(&cs[r * 132 + col * 4]) = v;
        }
        if (tid < 128) {
            int w = tid >> 5, i = tid & 31;
            int s2 = grp * 4 + w; if (s2 >= count) s2 = count - 1;
            int rw = g_list[s2];
            float4 v = reinterpret_cast<const float4*>(ze)[(size_t)rw * 32 + i];
            *reinterpret_cast<float4*>(&zs[w][i * 4]) = v;
        }
        __syncthreads();

        if (valid) {
            float4 zn = {0.f, 0.f, 0.f, 0.f};
            #pragma unroll
            for (int i = 0; i < 32; ++i) {
                float4 z = *reinterpret_cast<const float4*>(&zs[wv][i * 4]);
                zn.x += z.x * z.x; zn.y += z.y * z.y;
                zn.z += z.z * z.z; zn.w += z.w * z.w;
            }
            float znorm = (zn.x + zn.y) + (zn.z + zn.w);

            int k = chunk * 64 + lane;
            float4 a = {0.f, 0.f, 0.f, 0.f};
            #pragma unroll
            for (int i = 0; i < 32; ++i) {
                float4 c = *reinterpret_cast<const float4*>(&cs[lane * 132 + i * 4]);
                float4 z = *reinterpret_cast<const float4*>(&zs[wv][i * 4]);
                a.x += z.x * c.x; a.y += z.y * c.y;
                a.z += z.z * c.z; a.w += z.w * c.w;
            }
            float dot = (a.x + a.y) + (a.z + a.w);
            float s = fmaf(-2.f, dot, znorm + cs2[k].x);

            u64 p = ((u64)__float_as_uint(s) << 32) | (unsigned)k;
            #pragma unroll
            for (int o = 1; o < 64; o <<= 1) {
                u64 q = __shfl_xor(p, o);
                p = q < p ? q : p;
            }
            if (lane == 0) atomicMin(&g_res[row], p);
        }
        __syncthreads();
    }
}

// gather with fused fix: flagged rows (bit 31) read the rescued index.
__global__ void vq_gather(const float* __restrict__ cb,
                          const int* __restrict__ idx,
                          float* __restrict__ out) {
    size_t u = (size_t)blockIdx.x * blockDim.x + threadIdx.x;
    int r = (int)(u >> 5);
    int j = (int)(u & 31);
    int v = idx[r];
    if (v < 0) v = (int)(g_res[r] & 0xFFFFFFFFull);
    reinterpret_cast<float4*>(out)[u] =
        reinterpret_cast<const float4*>(cb)[((size_t)v << 5) + j];
}

extern "C" void kernel_launch(void* const* d_in, const int* in_sizes, int n_in,
                              void* d_out, int out_size, void* d_ws, size_t ws_size,
                              hipStream_t stream) {
    const float* ze = (const float*)d_in[0];
    const float* cb = (const float*)d_in[1];
    float* out = (float*)d_out;

    float2* cs2  = (float2*)d_ws;                      // 2048 float2 = 16 KB
    int*    bidx = (int*)((char*)d_ws + 16384);        // 65536 i32 = 256 KB

    vq_prepn<<<VQ_K * VQ_D / 8 / 256, 256, 0, stream>>>(cb, cs2);
    vq_score<<<VQ_M / 128, 256, 0, stream>>>(ze, cs2, bidx);
    vq_rescue<<<1024, 256, 0, stream>>>(ze, cb, cs2);
    vq_gather<<<(VQ_M * (VQ_D / 4)) / 256, 256, 0, stream>>>(cb, bidx, out);
}

// Round 11
// 106.102 us; speedup vs baseline: 1.1661x; 1.0612x over previous
//
#include <hip/hip_runtime.h>
#include <hip/hip_bf16.h>

// VQ quantizer: ze [65536 x 128] f32, codebook [2048 x 128] f32.
// out[m,:] = codebook[argmin_k ||z_m - c_k||^2, :]
//
// Round 18: R17 base (112.6 us total, vq_score 88, absmax 0) + two edits:
//  (1) XX accumulator split into XXa (aq1*bl) + XXb (aq2*bh): longest MFMA
//      dependency chain 8 -> 4 (distance 3). R17 proved VALU aggregate is
//      not the wall; with 2 waves/SIMD (grid-capped) the per-wave serial
//      chain is. Integer: (HH<<8)+XXa+XXb bit-identical to R17's
//      (HH<<8)+XX. Acc +16 regs -> predicted total ~124, under the
//      VGPR=128 occupancy cliff (R16 ok at 128, R11 fails at 132).
//  (2) THR 0.04 -> 0.02 (still 10 sigma of i8 err ~2e-3): rescue halves.
//  vq_prepn:  codebook -> 2-level i8 (pre-swizzled); cs2[k]={||c||^2, s1c}.
//  vq_score:  i8 MFMA scores, streaming top-2, flag margin < THR.
//  vq_rescue: exact-fp32 rescan of flagged rows, deterministic first-index.
//  vq_gather: out = codebook[idx], rescued rows (bit 31) read g_res.

#define VQ_D 128
#define VQ_K 2048
#define VQ_M 65536
#define VQ_THR 0.02f

typedef short short8 __attribute__((ext_vector_type(8)));
typedef int  int4v  __attribute__((ext_vector_type(4)));
typedef int  i32x16 __attribute__((ext_vector_type(16)));
typedef unsigned long long u64;

// codebook, 2-level i8, pre-swizzled: row r = 16 chunks of 16B; logical
// chunk c (0-7 = level-1 bytes, 8-15 = level-2 bytes) stored at position
// c ^ (r&15). 512 KB total.
__device__ uint4 g_cbi[VQ_K * 16];
__device__ int   g_list[VQ_M];
__device__ u64   g_res[VQ_M];
__device__ int   g_count;

// prep: thread g handles 8 elems of row g>>4 (16 threads/row)
__global__ void vq_prepn(const float* __restrict__ cb, float2* __restrict__ cs2) {
    int g = blockIdx.x * 256 + threadIdx.x;          // 0..32767
    int r = g >> 4, t = g & 15;
    const float4* s = reinterpret_cast<const float4*>(cb) + (size_t)g * 2;
    float4 f0 = s[0], f1 = s[1];
    float z[8] = {f0.x, f0.y, f0.z, f0.w, f1.x, f1.y, f1.z, f1.w};
    float ss = ((z[0]*z[0] + z[1]*z[1]) + (z[2]*z[2] + z[3]*z[3]))
             + ((z[4]*z[4] + z[5]*z[5]) + (z[6]*z[6] + z[7]*z[7]));
    float ax = fmaxf(fmaxf(fmaxf(fabsf(z[0]), fabsf(z[1])), fmaxf(fabsf(z[2]), fabsf(z[3]))),
                     fmaxf(fmaxf(fabsf(z[4]), fabsf(z[5])), fmaxf(fabsf(z[6]), fabsf(z[7]))));
    ss += __shfl_xor(ss, 1); ax = fmaxf(ax, __shfl_xor(ax, 1));
    ss += __shfl_xor(ss, 2); ax = fmaxf(ax, __shfl_xor(ax, 2));
    ss += __shfl_xor(ss, 4); ax = fmaxf(ax, __shfl_xor(ax, 4));
    ss += __shfl_xor(ss, 8); ax = fmaxf(ax, __shfl_xor(ax, 8));
    float mx  = fmaxf(ax, 1e-20f);
    float s1  = mx * (1.0f / 127.0f);
    float inv = 127.0f / mx;
    float inv2 = inv * 256.0f;
    int qa[8], qr[8];
    #pragma unroll
    for (int i = 0; i < 8; ++i) {
        float qf = rintf(z[i] * inv);
        float r1 = fmaf(-qf, s1, z[i]);
        float q2f = fminf(127.f, fmaxf(-127.f, rintf(r1 * inv2)));
        qa[i] = (int)qf; qr[i] = (int)q2f;
    }
    uint2 w1, w2;
    w1.x = (qa[0]&255) | ((qa[1]&255)<<8) | ((qa[2]&255)<<16) | ((unsigned)(qa[3]&255)<<24);
    w1.y = (qa[4]&255) | ((qa[5]&255)<<8) | ((qa[6]&255)<<16) | ((unsigned)(qa[7]&255)<<24);
    w2.x = (qr[0]&255) | ((qr[1]&255)<<8) | ((qr[2]&255)<<16) | ((unsigned)(qr[3]&255)<<24);
    w2.y = (qr[4]&255) | ((qr[5]&255)<<8) | ((qr[6]&255)<<16) | ((unsigned)(qr[7]&255)<<24);
    uint2* cw = reinterpret_cast<uint2*>(g_cbi);
    int c1 = (t >> 1) ^ (r & 15);
    int c2 = (8 + (t >> 1)) ^ (r & 15);
    cw[(r * 16 + c1) * 2 + (t & 1)] = w1;
    cw[(r * 16 + c2) * 2 + (t & 1)] = w2;
    if (t == 0) cs2[r] = make_float2(ss, s1);
    if (g == 0) g_count = 0;
}

__global__ __launch_bounds__(256, 2)
void vq_score(const float* __restrict__ ze,
              const float2* __restrict__ cs2,
              int* __restrict__ outIdx) {
    __shared__ uint4 sB[2048];   // 32 KB exactly: prologue A staging;
                                 // main loop: double-buffered B tile (2 x 16 KB).
    const int tid  = threadIdx.x;
    const int lane = tid & 63;
    const int wv   = tid >> 6;          // 0..3, wave owns 32 query rows
    const int ln31 = lane & 31;
    const int g2   = lane >> 5;         // 0/1: k-half selector
    const int qb   = blockIdx.x * 128;

    // ---- prologue: 2-level i8 quantize; rows are WAVE-OWNED:
    //      id = wv*512 + jj*64 + lane -> row r = wv*32 + jj*4 + (lane>>4)
    uint2 q1w[8], q2w[8];
    float s1r[8];                       // this lane's 16-group row scale, per jj
    #pragma unroll
    for (int jj = 0; jj < 8; ++jj) {
        int id = wv * 512 + jj * 64 + lane, r = id >> 4, t = id & 15;
        const float4* src =
            reinterpret_cast<const float4*>(ze + (size_t)(qb + r) * VQ_D + t * 8);
        float4 f0 = src[0], f1 = src[1];
        float z[8] = {f0.x, f0.y, f0.z, f0.w, f1.x, f1.y, f1.z, f1.w};
        float ax = fmaxf(fmaxf(fmaxf(fabsf(z[0]), fabsf(z[1])), fmaxf(fabsf(z[2]), fabsf(z[3]))),
                         fmaxf(fmaxf(fabsf(z[4]), fabsf(z[5])), fmaxf(fabsf(z[6]), fabsf(z[7]))));
        ax = fmaxf(ax, __shfl_xor(ax, 1));
        ax = fmaxf(ax, __shfl_xor(ax, 2));
        ax = fmaxf(ax, __shfl_xor(ax, 4));
        ax = fmaxf(ax, __shfl_xor(ax, 8));
        float mx  = fmaxf(ax, 1e-20f);
        float s1  = mx * (1.0f / 127.0f);
        float inv = 127.0f / mx;
        float inv2 = inv * 256.0f;
        s1r[jj] = s1;
        int qa[8], qr[8];
        #pragma unroll
        for (int i = 0; i < 8; ++i) {
            float qf = rintf(z[i] * inv);
            float r1 = fmaf(-qf, s1, z[i]);
            float q2f = fminf(127.f, fmaxf(-127.f, rintf(r1 * inv2)));
            qa[i] = (int)qf; qr[i] = (int)q2f;
        }
        q1w[jj].x = (qa[0]&255) | ((qa[1]&255)<<8) | ((qa[2]&255)<<16) | ((unsigned)(qa[3]&255)<<24);
        q1w[jj].y = (qa[4]&255) | ((qa[5]&255)<<8) | ((qa[6]&255)<<16) | ((unsigned)(qa[7]&255)<<24);
        q2w[jj].x = (qr[0]&255) | ((qr[1]&255)<<8) | ((qr[2]&255)<<16) | ((unsigned)(qr[3]&255)<<24);
        q2w[jj].y = (qr[4]&255) | ((qr[5]&255)<<8) | ((qr[6]&255)<<16) | ((unsigned)(qr[7]&255)<<24);
    }
    {
        uint2* sw = reinterpret_cast<uint2*>(sB);
        #pragma unroll
        for (int jj = 0; jj < 8; ++jj) {
            int id = wv * 512 + jj * 64 + lane, r = id >> 4, t = id & 15;
            int c1 = (t >> 1) ^ (r & 15);
            int c2 = (8 + (t >> 1)) ^ (r & 15);
            sw[(r * 16 + c1) * 2 + (t & 1)] = q1w[jj];
            sw[(r * 16 + c2) * 2 + (t & 1)] = q2w[jj];
        }
    }
    // per-row scale -> mj[j] via shfl (row rl = (j&3)+8*(j>>2)+4*g2;
    // held by lanes (rl&3)*16.. in s1r[rl>>2]; rl>>2 = 2*(j>>2)+g2)
    float mj[16];
    #pragma unroll
    for (int j = 0; j < 16; ++j) {
        float va = __shfl(s1r[2 * (j >> 2)],     (j & 3) << 4);
        float vb = __shfl(s1r[2 * (j >> 2) + 1], (j & 3) << 4);
        mj[j] = (g2 ? vb : va) * (-1.0f / 128.0f);
    }
    __syncthreads();
    int4v aq1[4], aq2[4];
    {
        int r = wv * 32 + ln31;
        #pragma unroll
        for (int kc = 0; kc < 4; ++kc) {
            int c = kc * 2 + g2;
            aq1[kc] = *(const int4v*)&sB[r * 16 + (c ^ (r & 15))];
            aq2[kc] = *(const int4v*)&sB[r * 16 + ((8 + c) ^ (r & 15))];
        }
    }
    __syncthreads();

    // ---- stage B tile (g_cbi pre-swizzled -> fully linear copy) ----
    #define STAGE_B(T, BUF)                                                     \
        _Pragma("unroll")                                                       \
        for (int jj = 0; jj < 4; ++jj) {                                        \
            int base = wv * 256 + jj * 64;                                      \
            __builtin_amdgcn_global_load_lds(                                   \
                (const void*)(g_cbi + (size_t)(T) * 1024 + base + lane),        \
                (void*)(sB + (BUF) * 1024 + base), 16, 0, 0);                   \
        }
    STAGE_B(0, 0)

    float m1[16], m2[16];
    int   i1[16];
    #pragma unroll
    for (int j = 0; j < 16; ++j) { m1[j] = 3.0e38f; m2[j] = 3.0e38f; i1[j] = 0; }

    // shared zero accumulator: C-operand of each half-pass's first MFMAs
    i32x16 Z;
    #pragma unroll
    for (int j = 0; j < 16; ++j) Z[j] = 0;

    float2 cf0 = cs2[ln31];
    float2 cf1 = cs2[32 + ln31];
    const int x15 = ln31 & 15;

    for (int tile = 0; tile < VQ_K / 64; ++tile) {
        // stage for this tile issued a full iteration ago -> drain cheap
        asm volatile("s_waitcnt vmcnt(0)" ::: "memory");
        __builtin_amdgcn_s_barrier();
        __builtin_amdgcn_sched_barrier(0);

        const int bb = (tile & 1) << 10;     // current buffer base (uint4 slots)

        if (tile < VQ_K / 64 - 1) { STAGE_B(tile + 1, (tile + 1) & 1) }
        int nt = (tile + 1) & (VQ_K / 64 - 1);
        float2 nf0 = cs2[nt * 64 + ln31];          // full-tile prefetch distance
        float2 nf1 = cs2[nt * 64 + 32 + ln31];

        int kb = tile * 64 + ln31;

        // ================= half-pass 0: code column ln31 =================
        {
            // 3 independent chains, each 4 deps at distance 3:
            //   HH  = sum aq1*bh;  XXb = sum aq2*bh;  XXa = sum aq1*bl
            i32x16 HH, XXa, XXb;
            __builtin_amdgcn_s_setprio(1);
            {   // kc = 0 peeled: C-in = Z (no acc zero-init movs)
                int c  = g2;
                int p1 = c ^ x15, p2 = (8 + c) ^ x15;
                int4v bh = *(const int4v*)&sB[bb + ln31 * 16 + p1];
                int4v bl = *(const int4v*)&sB[bb + ln31 * 16 + p2];
                XXb = __builtin_amdgcn_mfma_i32_32x32x32_i8(aq2[0], bh, Z, 0, 0, 0);
                HH  = __builtin_amdgcn_mfma_i32_32x32x32_i8(aq1[0], bh, Z, 0, 0, 0);
                XXa = __builtin_amdgcn_mfma_i32_32x32x32_i8(aq1[0], bl, Z, 0, 0, 0);
            }
            #pragma unroll
            for (int kc = 1; kc < 4; ++kc) {
                int c  = kc * 2 + g2;
                int p1 = c ^ x15, p2 = (8 + c) ^ x15;
                int4v bh = *(const int4v*)&sB[bb + ln31 * 16 + p1];
                int4v bl = *(const int4v*)&sB[bb + ln31 * 16 + p2];
                XXb = __builtin_amdgcn_mfma_i32_32x32x32_i8(aq2[kc], bh, XXb, 0, 0, 0);
                HH  = __builtin_amdgcn_mfma_i32_32x32x32_i8(aq1[kc], bh, HH, 0, 0, 0);
                XXa = __builtin_amdgcn_mfma_i32_32x32x32_i8(aq1[kc], bl, XXa, 0, 0, 0);
            }
            __builtin_amdgcn_s_setprio(0);

            #pragma unroll
            for (int j = 0; j < 16; ++j) {
                // integer: (HH<<8) + (XXa + XXb) == R17's (HH<<8) + XX exactly
                float s0 = fmaf((float)((HH[j] << 8) + (XXa[j] + XXb[j])) * cf0.y, mj[j], cf0.x);
                bool lt0 = s0 < m1[j];
                m2[j] = __builtin_amdgcn_fmed3f(s0, m1[j], m2[j]);
                i1[j] = lt0 ? kb : i1[j];
                m1[j] = fminf(m1[j], s0);
            }
        }

        // ================= half-pass 1: code column 32+ln31 ==============
        {
            i32x16 HH, XXa, XXb;
            __builtin_amdgcn_s_setprio(1);
            {   // kc = 0 peeled: C-in = Z
                int c  = g2;
                int p1 = c ^ x15, p2 = (8 + c) ^ x15;
                int4v bh = *(const int4v*)&sB[bb + (32 + ln31) * 16 + p1];
                int4v bl = *(const int4v*)&sB[bb + (32 + ln31) * 16 + p2];
                XXb = __builtin_amdgcn_mfma_i32_32x32x32_i8(aq2[0], bh, Z, 0, 0, 0);
                HH  = __builtin_amdgcn_mfma_i32_32x32x32_i8(aq1[0], bh, Z, 0, 0, 0);
                XXa = __builtin_amdgcn_mfma_i32_32x32x32_i8(aq1[0], bl, Z, 0, 0, 0);
            }
            #pragma unroll
            for (int kc = 1; kc < 4; ++kc) {
                int c  = kc * 2 + g2;
                int p1 = c ^ x15, p2 = (8 + c) ^ x15;
                int4v bh = *(const int4v*)&sB[bb + (32 + ln31) * 16 + p1];
                int4v bl = *(const int4v*)&sB[bb + (32 + ln31) * 16 + p2];
                XXb = __builtin_amdgcn_mfma_i32_32x32x32_i8(aq2[kc], bh, XXb, 0, 0, 0);
                HH  = __builtin_amdgcn_mfma_i32_32x32x32_i8(aq1[kc], bh, HH, 0, 0, 0);
                XXa = __builtin_amdgcn_mfma_i32_32x32x32_i8(aq1[kc], bl, XXa, 0, 0, 0);
            }
            __builtin_amdgcn_s_setprio(0);

            #pragma unroll
            for (int j = 0; j < 16; ++j) {
                float s1v = fmaf((float)((HH[j] << 8) + (XXa[j] + XXb[j])) * cf1.y, mj[j], cf1.x);
                bool lt1 = s1v < m1[j];
                m2[j] = __builtin_amdgcn_fmed3f(s1v, m1[j], m2[j]);
                i1[j] = lt1 ? kb + 32 : i1[j];
                m1[j] = fminf(m1[j], s1v);
            }
        }

        cf0 = nf0; cf1 = nf1;
    }

    // ---- cross-lane top-2 merge over the 32-lane code groups (g2 fixed) ----
    #pragma unroll
    for (int j = 0; j < 16; ++j) {
        float a1v = m1[j], a2v = m2[j];
        int   ai  = i1[j];
        #pragma unroll
        for (int off = 1; off < 32; off <<= 1) {
            float o1 = __shfl_xor(a1v, off);
            float o2 = __shfl_xor(a2v, off);
            int   oi = __shfl_xor(ai, off);
            bool lt = o1 < a1v;
            float hi = lt ? a1v : o1;
            a1v = lt ? o1 : a1v;
            ai  = lt ? oi : ai;
            a2v = fminf(fminf(a2v, o2), hi);
            // exact inter-lane tie -> a2v==a1v -> flagged -> rescued
        }
        if (ln31 == 0) {
            int row = qb + wv * 32 + (j & 3) + 8 * (j >> 2) + 4 * g2;
            if (a2v - a1v < VQ_THR) {
                outIdx[row] = (int)((unsigned)ai | 0x80000000u);   // flag bit 31
                g_res[row] = ~0ull;
                int pos = atomicAdd(&g_count, 1);
                g_list[pos] = row;
            } else {
                outIdx[row] = ai;
            }
        }
    }
    #undef STAGE_B
}

__global__ __launch_bounds__(256)
void vq_rescue(const float* __restrict__ ze,
               const float* __restrict__ cb,
               const float2* __restrict__ cs2) {
    __shared__ float cs[64 * 132];    // 64 codes x 128, padded +4
    __shared__ float zs[4][128];      // 4 flagged rows

    const int tid  = threadIdx.x;
    const int lane = tid & 63;
    const int wv   = tid >> 6;          // 0..3: one flagged row per wave
    const int count = g_count;
    const long nitems = (long)((count + 3) >> 2) * 32;

    for (long it = blockIdx.x; it < nitems; it += gridDim.x) {
        const int grp   = (int)(it >> 5);
        const int chunk = (int)(it & 31);
        const int slot  = grp * 4 + wv;
        const bool valid = slot < count;
        const int row = g_list[valid ? slot : (count - 1)];

        #pragma unroll
        for (int j = 0; j < 8; ++j) {
            int id = j * 256 + tid;
            int r = id >> 5, col = id & 31;
            float4 v = reinterpret_cast<const float4*>(cb)[(size_t)(chunk * 64 + r) * 32 + col];
            *reinterpret_cast<float4*>(&cs[r * 132 + col * 4]) = v;
        }
        if (tid < 128) {
            int w = tid >> 5, i = tid & 31;
            int s2 = grp * 4 + w; if (s2 >= count) s2 = count - 1;
            int rw = g_list[s2];
            float4 v = reinterpret_cast<const float4*>(ze)[(size_t)rw * 32 + i];
            *reinterpret_cast<float4*>(&zs[w][i * 4]) = v;
        }
        __syncthreads();

        if (valid) {
            float4 zn = {0.f, 0.f, 0.f, 0.f};
            #pragma unroll
            for (int i = 0; i < 32; ++i) {
                float4 z = *reinterpret_cast<const float4*>(&zs[wv][i * 4]);
                zn.x += z.x * z.x; zn.y += z.y * z.y;
                zn.z += z.z * z.z; zn.w += z.w * z.w;
            }
            float znorm = (zn.x + zn.y) + (zn.z + zn.w);

            int k = chunk * 64 + lane;
            float4 a = {0.f, 0.f, 0.f, 0.f};
            #pragma unroll
            for (int i = 0; i < 32; ++i) {
                float4 c = *reinterpret_cast<const float4*>(&cs[lane * 132 + i * 4]);
                float4 z = *reinterpret_cast<const float4*>(&zs[wv][i * 4]);
                a.x += z.x * c.x; a.y += z.y * c.y;
                a.z += z.z * c.z; a.w += z.w * c.w;
            }
            float dot = (a.x + a.y) + (a.z + a.w);
            float s = fmaf(-2.f, dot, znorm + cs2[k].x);

            u64 p = ((u64)__float_as_uint(s) << 32) | (unsigned)k;
            #pragma unroll
            for (int o = 1; o < 64; o <<= 1) {
                u64 q = __shfl_xor(p, o);
                p = q < p ? q : p;
            }
            if (lane == 0) atomicMin(&g_res[row], p);
        }
        __syncthreads();
    }
}

// gather with fused fix: flagged rows (bit 31) read the rescued index.
__global__ void vq_gather(const float* __restrict__ cb,
                          const int* __restrict__ idx,
                          float* __restrict__ out) {
    size_t u = (size_t)blockIdx.x * blockDim.x + threadIdx.x;
    int r = (int)(u >> 5);
    int j = (int)(u & 31);
    int v = idx[r];
    if (v < 0) v = (int)(g_res[r] & 0xFFFFFFFFull);
    reinterpret_cast<float4*>(out)[u] =
        reinterpret_cast<const float4*>(cb)[((size_t)v << 5) + j];
}

extern "C" void kernel_launch(void* const* d_in, const int* in_sizes, int n_in,
                              void* d_out, int out_size, void* d_ws, size_t ws_size,
                              hipStream_t stream) {
    const float* ze = (const float*)d_in[0];
    const float* cb = (const float*)d_in[1];
    float* out = (float*)d_out;

    float2* cs2  = (float2*)d_ws;                      // 2048 float2 = 16 KB
    int*    bidx = (int*)((char*)d_ws + 16384);        // 65536 i32 = 256 KB

    vq_prepn<<<VQ_K * VQ_D / 8 / 256, 256, 0, stream>>>(cb, cs2);
    vq_score<<<VQ_M / 128, 256, 0, stream>>>(ze, cs2, bidx);
    vq_rescue<<<1024, 256, 0, stream>>>(ze, cb, cs2);
    vq_gather<<<(VQ_M * (VQ_D / 4)) / 256, 256, 0, stream>>>(cb, bidx, out);
}